// Round 2
// baseline (491.068 us; speedup 1.0000x reference)
//
#include <hip/hip_runtime.h>
#include <cstddef>
#include <cstdint>

#define HIDV 256
#define KR 64
#define NH 4
#define DHV 64

__device__ __forceinline__ float dot4(float4 a, float4 b) {
  return a.x*b.x + a.y*b.y + a.z*b.z + a.w*b.w;
}

// DPP-based add of lane-moved value (VALU pipe, no LDS traffic)
template<int CTRL>
__device__ __forceinline__ float dppadd(float v) {
  int m = __builtin_amdgcn_update_dpp(0, __float_as_int(v), CTRL, 0xf, 0xf, true);
  return v + __int_as_float(m);
}
// full 64-lane sum, result in all lanes: 4 DPP (VALU) + 2 cross-group shuffles
__device__ __forceinline__ float red64f(float v) {
  v = dppadd<0xB1>(v);    // quad_perm xor1
  v = dppadd<0x4E>(v);    // quad_perm xor2
  v = dppadd<0x124>(v);   // row_ror:4
  v = dppadd<0x128>(v);   // row_ror:8
  v += __shfl_xor(v, 16);
  v += __shfl_xor(v, 32);
  return v;
}

// ---------------- K0: q, qk = q @ wk_head, learned anomaly ----------------
#define R0 8
__global__ __launch_bounds__(256) void k0_mlp_qk(
    const float* __restrict__ msg,
    const float* __restrict__ w_ad1, const float* __restrict__ b_ad1,
    const float* __restrict__ w_ad2, const float* __restrict__ b_ad2,
    const float* __restrict__ ipw, const float* __restrict__ ipb,
    float* __restrict__ qk_ws, float* __restrict__ la_ws, int B)
{
  __shared__ float msg_s[R0][HIDV];
  __shared__ float q_s[R0][HIDV];
  __shared__ float redw[4][R0];
  const int t = threadIdx.x;
  const int lane = t & 63, wv = t >> 6;
  const int b0 = blockIdx.x * R0;

  #pragma unroll
  for (int r = 0; r < R0; ++r) {
    int b = b0 + r;
    msg_s[r][t] = (b < B) ? msg[(size_t)b*HIDV + t] : 0.f;
  }
  __syncthreads();

  // q[r][t] = bq[t] + msg[r] . wq_row[t]
  {
    float acc[R0];
    float bq = ipb[t];
    #pragma unroll
    for (int r = 0; r < R0; ++r) acc[r] = bq;
    const float4* wrow = reinterpret_cast<const float4*>(ipw + (size_t)t*HIDV);
    #pragma unroll 4
    for (int c4 = 0; c4 < HIDV/4; ++c4) {
      float4 w = wrow[c4];
      #pragma unroll
      for (int r = 0; r < R0; ++r)
        acc[r] += dot4(w, reinterpret_cast<const float4*>(msg_s[r])[c4]);
    }
    #pragma unroll
    for (int r = 0; r < R0; ++r) q_s[r][t] = acc[r];
  }
  __syncthreads();

  // qk[r][h][t] = sum_d q[r][h*64+d] * wk[h*64+d][t]
  for (int h = 0; h < NH; ++h) {
    float acc[R0];
    #pragma unroll
    for (int r = 0; r < R0; ++r) acc[r] = 0.f;
    #pragma unroll 2
    for (int d4 = 0; d4 < DHV/4; ++d4) {
      const float* wp = ipw + (size_t)(HIDV + h*DHV + d4*4)*HIDV + t;
      float w0 = wp[0];
      float w1 = wp[HIDV];
      float w2 = wp[2*HIDV];
      float w3 = wp[3*HIDV];
      #pragma unroll
      for (int r = 0; r < R0; ++r) {
        float4 q4 = *reinterpret_cast<const float4*>(&q_s[r][h*DHV + d4*4]);
        acc[r] += q4.x*w0 + q4.y*w1 + q4.z*w2 + q4.w*w3;
      }
    }
    #pragma unroll
    for (int r = 0; r < R0; ++r) {
      int b = b0 + r;
      if (b < B) qk_ws[(size_t)b*(NH*HIDV) + h*HIDV + t] = acc[r];
    }
  }

  // learned anomaly: sigmoid(relu(msg@w_ad1.T+b).w_ad2 + b)
  {
    float prod[R0];
    if (t < 128) {
      float h1[R0];
      float bb = b_ad1[t];
      #pragma unroll
      for (int r = 0; r < R0; ++r) h1[r] = bb;
      const float4* wrow = reinterpret_cast<const float4*>(w_ad1 + (size_t)t*HIDV);
      #pragma unroll 4
      for (int c4 = 0; c4 < HIDV/4; ++c4) {
        float4 w = wrow[c4];
        #pragma unroll
        for (int r = 0; r < R0; ++r)
          h1[r] += dot4(w, reinterpret_cast<const float4*>(msg_s[r])[c4]);
      }
      float wa2 = w_ad2[t];
      #pragma unroll
      for (int r = 0; r < R0; ++r) prod[r] = fmaxf(h1[r], 0.f) * wa2;
    } else {
      #pragma unroll
      for (int r = 0; r < R0; ++r) prod[r] = 0.f;
    }
    #pragma unroll
    for (int r = 0; r < R0; ++r) prod[r] = red64f(prod[r]);
    if (lane == 0) {
      #pragma unroll
      for (int r = 0; r < R0; ++r) redw[wv][r] = prod[r];
    }
    __syncthreads();
    if (t < R0) {
      int b = b0 + t;
      if (b < B) {
        float x = redw[0][t] + redw[1][t] + redw[2][t] + redw[3][t] + b_ad2[0];
        la_ws[b] = 1.f / (1.f + expf(-x));
      }
    }
  }
}

// ---------------- K1: stream storage: stats + updated[1..63] + online attn ----------------
__global__ __launch_bounds__(256) void k1_stream(
    const float* __restrict__ storage, const float* __restrict__ msg,
    const float* __restrict__ qk_ws,
    float* __restrict__ upd,
    float* __restrict__ mean_ws, float* __restrict__ pv_ws,
    float* __restrict__ se_ws, float* __restrict__ s0c_ws,
    float* __restrict__ stat_ws, int B)
{
  __shared__ float qk_s[NH][HIDV];
  __shared__ float msg_s[HIDV];
  __shared__ float dw_s[KR];
  __shared__ float s1_s[4][HIDV];
  __shared__ float s2_s[4][HIDV];
  __shared__ float pv_s[4][NH][HIDV];
  __shared__ float se_s[4][NH];
  __shared__ int cnt_s[4];
  __shared__ float red4[4][NH];
  __shared__ float redi[4];

  const int t = threadIdx.x, lane = t & 63, wv = t >> 6;
  const int b = blockIdx.x;

  #pragma unroll
  for (int i = 0; i < NH; ++i)
    (&qk_s[0][0])[i*256 + t] = qk_ws[(size_t)b*(NH*HIDV) + i*256 + t];
  msg_s[t] = msg[(size_t)b*HIDV + t];
  if (t < KR) dw_s[t] = exp2f((float)t * -0.07400058f);  // 0.95^t
  __syncthreads();

  // s0coef[h] = sum_c qk[h][c]*msg[c]
  {
    float p[NH];
    #pragma unroll
    for (int h = 0; h < NH; ++h) p[h] = red64f(qk_s[h][t] * msg_s[t]);
    if (lane == 0) {
      #pragma unroll
      for (int h = 0; h < NH; ++h) red4[wv][h] = p[h];
    }
  }
  const int c0 = lane * 4;
  float qkr[NH][4];
  #pragma unroll
  for (int h = 0; h < NH; ++h) {
    float4 v = *reinterpret_cast<const float4*>(&qk_s[h][c0]);
    qkr[h][0] = v.x; qkr[h][1] = v.y; qkr[h][2] = v.z; qkr[h][3] = v.w;
  }
  __syncthreads();
  if (t < NH)
    s0c_ws[(size_t)b*NH + t] = red4[0][t] + red4[1][t] + red4[2][t] + red4[3][t];

  float S1[4] = {0.f,0.f,0.f,0.f}, S2[4] = {0.f,0.f,0.f,0.f};
  float pv[NH][4];
  float se[NH] = {0.f,0.f,0.f,0.f};
  #pragma unroll
  for (int h = 0; h < NH; ++h) {
    #pragma unroll
    for (int i = 0; i < 4; ++i) pv[h][i] = 0.f;
  }
  int cnt = 0;

  const float* __restrict__ srow = storage + (size_t)b*KR*HIDV;
  float* __restrict__ urow = upd + (size_t)b*KR*HIDV;

  float4 x[4];
  {
    const int r0 = wv*16;
    #pragma unroll
    for (int rr = 0; rr < 4; ++rr)
      x[rr] = *reinterpret_cast<const float4*>(srow + (size_t)(r0+rr)*HIDV + c0);
  }

  for (int it = 0; it < 4; ++it) {
    const int r0 = wv*16 + it*4;
    float4 xn[4];
    if (it < 3) {
      #pragma unroll
      for (int rr = 0; rr < 4; ++rr)
        xn[rr] = *reinterpret_cast<const float4*>(srow + (size_t)(r0+4+rr)*HIDV + c0);
    }

    // row mask via ballot (exact: any element nonzero)
    unsigned long long bal[4];
    #pragma unroll
    for (int rr = 0; rr < 4; ++rr)
      bal[rr] = __ballot(x[rr].x != 0.f || x[rr].y != 0.f ||
                         x[rr].z != 0.f || x[rr].w != 0.f);

    float dwv[4], fct[4];
    #pragma unroll
    for (int rr = 0; rr < 4; ++rr) {
      dwv[rr] = dw_s[r0+rr];
      fct[rr] = dwv[rr] * 0.125f;
    }

    float sp[4][NH];
    #pragma unroll
    for (int rr = 0; rr < 4; ++rr) {
      const int j = r0 + rr;
      if (bal[rr]) {  // wave-uniform
        cnt++;
        S1[0]+=x[rr].x; S1[1]+=x[rr].y; S1[2]+=x[rr].z; S1[3]+=x[rr].w;
        S2[0]+=x[rr].x*x[rr].x; S2[1]+=x[rr].y*x[rr].y;
        S2[2]+=x[rr].z*x[rr].z; S2[3]+=x[rr].w*x[rr].w;
      }
      float dw = dwv[rr];
      if (j < KR-1) {
        float4 u;
        u.x = x[rr].x*dw; u.y = x[rr].y*dw; u.z = x[rr].z*dw; u.w = x[rr].w*dw;
        *reinterpret_cast<float4*>(urow + (size_t)(j+1)*HIDV + c0) = u;
      }
      #pragma unroll
      for (int h = 0; h < NH; ++h)
        sp[rr][h] = qkr[h][0]*x[rr].x + qkr[h][1]*x[rr].y
                  + qkr[h][2]*x[rr].z + qkr[h][3]*x[rr].w;
    }
    // 16 independent 64-lane reductions (DPP + 2 shuffles each)
    #pragma unroll
    for (int rr = 0; rr < 4; ++rr) {
      #pragma unroll
      for (int h = 0; h < NH; ++h)
        sp[rr][h] = red64f(sp[rr][h]);
    }
    #pragma unroll
    for (int rr = 0; rr < 4; ++rr) {
      const int j = r0 + rr;
      if (j < KR-1) {  // storage row 63 is dropped from updated -> no score
        #pragma unroll
        for (int h = 0; h < NH; ++h) {
          float e = __expf(sp[rr][h] * fct[rr]);   // exp(score_u * 0.125)
          se[h] += e;
          float ed = e * dwv[rr];                  // e * u = ed * x
          pv[h][0] += ed*x[rr].x; pv[h][1] += ed*x[rr].y;
          pv[h][2] += ed*x[rr].z; pv[h][3] += ed*x[rr].w;
        }
      }
    }
    if (it < 3) {
      #pragma unroll
      for (int rr = 0; rr < 4; ++rr) x[rr] = xn[rr];
    }
  }

  #pragma unroll
  for (int i = 0; i < 4; ++i) { s1_s[wv][c0+i] = S1[i]; s2_s[wv][c0+i] = S2[i]; }
  #pragma unroll
  for (int h = 0; h < NH; ++h) {
    #pragma unroll
    for (int i = 0; i < 4; ++i) pv_s[wv][h][c0+i] = pv[h][i];
  }
  if (lane == 0) {
    #pragma unroll
    for (int h = 0; h < NH; ++h) se_s[wv][h] = se[h];
    cnt_s[wv] = cnt;
  }
  __syncthreads();

  float s1 = s1_s[0][t]+s1_s[1][t]+s1_s[2][t]+s1_s[3][t];
  float s2 = s2_s[0][t]+s2_s[1][t]+s2_s[2][t]+s2_s[3][t];
  int ctot = cnt_s[0]+cnt_s[1]+cnt_s[2]+cnt_s[3];
  float msum = (float)ctot + 1e-8f;
  float mn = s1 / msum;
  mean_ws[(size_t)b*HIDV + t] = mn;
  float varn = s2 - 2.f*mn*s1 + mn*mn*(float)ctot;
  float sd = sqrtf(fmaxf(varn, 0.f) / msum);
  float z = fabsf((msg_s[t] - mn) / (sd + 1e-8f));
  float ind = red64f((z > 2.0f) ? 1.f : 0.f);
  if (lane == 0) redi[wv] = ind;
  #pragma unroll
  for (int h = 0; h < NH; ++h)
    pv_ws[(size_t)b*(NH*HIDV) + h*HIDV + t] =
        pv_s[0][h][t]+pv_s[1][h][t]+pv_s[2][h][t]+pv_s[3][h][t];
  if (t < NH)
    se_ws[(size_t)b*NH + t] = se_s[0][t]+se_s[1][t]+se_s[2][t]+se_s[3][t];
  __syncthreads();
  if (t == 0)
    stat_ws[b] = (redi[0]+redi[1]+redi[2]+redi[3]) * (1.f/256.f);
}

// ---------------- K3: imp MLP, row0, finish softmax, pooled V + out proj ----------------
__global__ __launch_bounds__(256) void k3_out(
    const float* __restrict__ msg,
    const float* __restrict__ mean_ws, const float* __restrict__ pv_ws,
    const float* __restrict__ se_ws, const float* __restrict__ s0c_ws,
    const float* __restrict__ stat_ws, const float* __restrict__ la_ws,
    const float* __restrict__ w_im1, const float* __restrict__ b_im1,
    const float* __restrict__ w_im2, const float* __restrict__ b_im2,
    const float* __restrict__ ipw, const float* __restrict__ ipb,
    const float* __restrict__ opw, const float* __restrict__ opb,
    float* __restrict__ upd, float* __restrict__ agg, int B)
{
  __shared__ float msg_s[8][HIDV];
  __shared__ float mc_s[8][HIDV];      // mean in phase1, ctx in phase3
  __shared__ float pu_s[8][NH*HIDV];
  __shared__ float redw[4][8];
  __shared__ float imp_s[8];
  __shared__ float se_sh[8][NH];
  __shared__ float s0_sh[8][NH];

  const int t = threadIdx.x, lane = t & 63, wv = t >> 6;
  const int b0 = blockIdx.x * 8;

  #pragma unroll
  for (int r = 0; r < 8; ++r) {
    int b = b0 + r;
    msg_s[r][t] = (b < B) ? msg[(size_t)b*HIDV + t] : 0.f;
    mc_s[r][t]  = (b < B) ? mean_ws[(size_t)b*HIDV + t] : 0.f;
  }
  if (t < 8*NH) {
    int r = t >> 2, h = t & 3;
    int b = b0 + r;
    se_sh[r][h] = (b < B) ? se_ws[(size_t)b*NH + h] : 0.f;
    s0_sh[r][h] = (b < B) ? s0c_ws[(size_t)b*NH + h] : 0.f;
  }
  __syncthreads();

  // g = relu([msg,mean] @ w_im1.T + b), imp = softplus(g.w_im2+b)*(1+anom)
  {
    float g[8];
    float bi = b_im1[t];
    #pragma unroll
    for (int r = 0; r < 8; ++r) g[r] = bi;
    const float4* w1 = reinterpret_cast<const float4*>(w_im1 + (size_t)t*(2*HIDV));
    #pragma unroll 4
    for (int c4 = 0; c4 < HIDV/4; ++c4) {
      float4 w = w1[c4];
      #pragma unroll
      for (int r = 0; r < 8; ++r)
        g[r] += dot4(w, reinterpret_cast<const float4*>(msg_s[r])[c4]);
    }
    #pragma unroll 4
    for (int c4 = 0; c4 < HIDV/4; ++c4) {
      float4 w = w1[HIDV/4 + c4];
      #pragma unroll
      for (int r = 0; r < 8; ++r)
        g[r] += dot4(w, reinterpret_cast<const float4*>(mc_s[r])[c4]);
    }
    float w2 = w_im2[t];
    float prod[8];
    #pragma unroll
    for (int r = 0; r < 8; ++r) prod[r] = red64f(fmaxf(g[r], 0.f) * w2);
    if (lane == 0) {
      #pragma unroll
      for (int r = 0; r < 8; ++r) redw[wv][r] = prod[r];
    }
    __syncthreads();
    if (t < 8) {
      int b = b0 + t;
      float x = redw[0][t]+redw[1][t]+redw[2][t]+redw[3][t] + b_im2[0];
      float sp = fmaxf(x, 0.f) + log1pf(expf(-fabsf(x)));
      float an = (b < B) ? (0.5f*stat_ws[b] + 0.5f*la_ws[b]) : 0.f;
      imp_s[t] = sp * (1.f + an);
    }
    __syncthreads();
  }

  // row0 of updated + pu = attn0*u0 + pv1/denom
  #pragma unroll
  for (int r = 0; r < 8; ++r) {
    int b = b0 + r;
    if (b < B) upd[(size_t)b*KR*HIDV + t] = msg_s[r][t] * imp_s[r];
  }
  #pragma unroll
  for (int r = 0; r < 8; ++r) {
    int b = b0 + r; if (b >= B) b = B - 1;
    float impr = imp_s[r];
    #pragma unroll
    for (int h = 0; h < NH; ++h) {
      float s0 = impr * s0_sh[r][h] * 0.125f;
      float e0 = __expf(s0);
      float den = e0 + se_sh[r][h];
      float inv = 1.f / den;
      float a0 = e0 * inv;
      pu_s[r][h*HIDV + t] = a0*impr*msg_s[r][t]
                          + pv_ws[(size_t)b*(NH*HIDV) + h*HIDV + t]*inv;
    }
  }
  __syncthreads();

  // ctx_out[t] = bv[t] + wv_row[t] . pu[head(t)]   (into mc_s)
  {
    float co[8];
    float bv = ipb[2*HIDV + t];
    #pragma unroll
    for (int r = 0; r < 8; ++r) co[r] = bv;
    const int hh = t >> 6;
    const float4* wrow = reinterpret_cast<const float4*>(ipw + (size_t)(2*HIDV + t)*HIDV);
    #pragma unroll 4
    for (int c4 = 0; c4 < HIDV/4; ++c4) {
      float4 w = wrow[c4];
      #pragma unroll
      for (int r = 0; r < 8; ++r)
        co[r] += dot4(w, reinterpret_cast<const float4*>(&pu_s[r][hh*HIDV])[c4]);
    }
    __syncthreads();
    #pragma unroll
    for (int r = 0; r < 8; ++r) mc_s[r][t] = co[r];
  }
  __syncthreads();

  // aggregated = ctx_out @ out_w.T + out_b
  {
    float ag[8];
    float bo = opb[t];
    #pragma unroll
    for (int r = 0; r < 8; ++r) ag[r] = bo;
    const float4* wrow = reinterpret_cast<const float4*>(opw + (size_t)t*HIDV);
    #pragma unroll 4
    for (int c4 = 0; c4 < HIDV/4; ++c4) {
      float4 w = wrow[c4];
      #pragma unroll
      for (int r = 0; r < 8; ++r)
        ag[r] += dot4(w, reinterpret_cast<const float4*>(mc_s[r])[c4]);
    }
    #pragma unroll
    for (int r = 0; r < 8; ++r) {
      int b = b0 + r;
      if (b < B) agg[(size_t)b*HIDV + t] = ag[r];
    }
  }
}

extern "C" void kernel_launch(void* const* d_in, const int* in_sizes, int n_in,
                              void* d_out, int out_size, void* d_ws, size_t ws_size,
                              hipStream_t stream) {
  const float* storage = (const float*)d_in[0];
  const float* msg     = (const float*)d_in[1];
  const float* w_ad1   = (const float*)d_in[2];
  const float* b_ad1   = (const float*)d_in[3];
  const float* w_ad2   = (const float*)d_in[4];
  const float* b_ad2   = (const float*)d_in[5];
  const float* w_im1   = (const float*)d_in[6];
  const float* b_im1   = (const float*)d_in[7];
  const float* w_im2   = (const float*)d_in[8];
  const float* b_im2   = (const float*)d_in[9];
  const float* ipw     = (const float*)d_in[10];
  const float* ipb     = (const float*)d_in[11];
  const float* opw     = (const float*)d_in[12];
  const float* opb     = (const float*)d_in[13];

  const int B = in_sizes[1] / HIDV;
  float* upd = (float*)d_out;
  float* agg = upd + (size_t)B*KR*HIDV;

  float* wsf = (float*)d_ws;
  size_t off = 0;
  float* qk   = wsf + off; off += (size_t)B*NH*HIDV;
  float* pv1  = wsf + off; off += (size_t)B*NH*HIDV;
  float* mean = wsf + off; off += (size_t)B*HIDV;
  float* se1  = wsf + off; off += (size_t)B*NH;
  float* s0c  = wsf + off; off += (size_t)B*NH;
  float* stat = wsf + off; off += (size_t)B;
  float* la   = wsf + off; off += (size_t)B;

  hipLaunchKernelGGL(k0_mlp_qk, dim3((B+R0-1)/R0), dim3(256), 0, stream,
                     msg, w_ad1, b_ad1, w_ad2, b_ad2, ipw, ipb, qk, la, B);
  hipLaunchKernelGGL(k1_stream, dim3(B), dim3(256), 0, stream,
                     storage, msg, qk, upd, mean, pv1, se1, s0c, stat, B);
  hipLaunchKernelGGL(k3_out, dim3((B+7)/8), dim3(256), 0, stream,
                     msg, mean, pv1, se1, s0c, stat, la,
                     w_im1, b_im1, w_im2, b_im2, ipw, ipb, opw, opb,
                     upd, agg, B);
}

// Round 3
// 473.342 us; speedup vs baseline: 1.0374x; 1.0374x over previous
//
#include <hip/hip_runtime.h>
#include <cstddef>
#include <cstdint>

#define HIDV 256
#define KR 64
#define NH 4
#define DHV 64

typedef float f4 __attribute__((ext_vector_type(4)));

__device__ __forceinline__ float dot4(float4 a, float4 b) {
  return a.x*b.x + a.y*b.y + a.z*b.z + a.w*b.w;
}
__device__ __forceinline__ float dotf4(f4 a, f4 b) {
  return a.x*b.x + a.y*b.y + a.z*b.z + a.w*b.w;
}
__device__ __forceinline__ f4 ntload4(const float* p) {
  return __builtin_nontemporal_load(reinterpret_cast<const f4*>(p));
}
__device__ __forceinline__ void ntstore4(float* p, f4 v) {
  __builtin_nontemporal_store(v, reinterpret_cast<f4*>(p));
}

// DPP-based add of lane-moved value (VALU pipe, no LDS traffic)
template<int CTRL>
__device__ __forceinline__ float dppadd(float v) {
  int m = __builtin_amdgcn_update_dpp(0, __float_as_int(v), CTRL, 0xf, 0xf, true);
  return v + __int_as_float(m);
}
// full 64-lane sum, result in all lanes
__device__ __forceinline__ float red64f(float v) {
  v = dppadd<0xB1>(v);    // quad_perm xor1
  v = dppadd<0x4E>(v);    // quad_perm xor2
  v = dppadd<0x124>(v);   // row_ror:4
  v = dppadd<0x128>(v);   // row_ror:8
  v += __shfl_xor(v, 16);
  v += __shfl_xor(v, 32);
  return v;
}

// ---------------- K0: q, qk = q @ wk_head, learned anomaly ----------------
#define R0 8
__global__ __launch_bounds__(256) void k0_mlp_qk(
    const float* __restrict__ msg,
    const float* __restrict__ w_ad1, const float* __restrict__ b_ad1,
    const float* __restrict__ w_ad2, const float* __restrict__ b_ad2,
    const float* __restrict__ ipw, const float* __restrict__ ipb,
    float* __restrict__ qk_ws, float* __restrict__ la_ws, int B)
{
  __shared__ float msg_s[R0][HIDV];
  __shared__ float q_s[R0][HIDV];
  __shared__ float redw[4][R0];
  const int t = threadIdx.x;
  const int lane = t & 63, wv = t >> 6;
  const int b0 = blockIdx.x * R0;

  #pragma unroll
  for (int r = 0; r < R0; ++r) {
    int b = b0 + r;
    msg_s[r][t] = (b < B) ? msg[(size_t)b*HIDV + t] : 0.f;
  }
  __syncthreads();

  // q[r][t] = bq[t] + msg[r] . wq_row[t]
  {
    float acc[R0];
    float bq = ipb[t];
    #pragma unroll
    for (int r = 0; r < R0; ++r) acc[r] = bq;
    const float4* wrow = reinterpret_cast<const float4*>(ipw + (size_t)t*HIDV);
    #pragma unroll 4
    for (int c4 = 0; c4 < HIDV/4; ++c4) {
      float4 w = wrow[c4];
      #pragma unroll
      for (int r = 0; r < R0; ++r)
        acc[r] += dot4(w, reinterpret_cast<const float4*>(msg_s[r])[c4]);
    }
    #pragma unroll
    for (int r = 0; r < R0; ++r) q_s[r][t] = acc[r];
  }
  __syncthreads();

  // qk[r][h][t] = sum_d q[r][h*64+d] * wk[h*64+d][t]
  for (int h = 0; h < NH; ++h) {
    float acc[R0];
    #pragma unroll
    for (int r = 0; r < R0; ++r) acc[r] = 0.f;
    #pragma unroll 2
    for (int d4 = 0; d4 < DHV/4; ++d4) {
      const float* wp = ipw + (size_t)(HIDV + h*DHV + d4*4)*HIDV + t;
      float w0 = wp[0];
      float w1 = wp[HIDV];
      float w2 = wp[2*HIDV];
      float w3 = wp[3*HIDV];
      #pragma unroll
      for (int r = 0; r < R0; ++r) {
        float4 q4 = *reinterpret_cast<const float4*>(&q_s[r][h*DHV + d4*4]);
        acc[r] += q4.x*w0 + q4.y*w1 + q4.z*w2 + q4.w*w3;
      }
    }
    #pragma unroll
    for (int r = 0; r < R0; ++r) {
      int b = b0 + r;
      if (b < B) qk_ws[(size_t)b*(NH*HIDV) + h*HIDV + t] = acc[r];
    }
  }

  // learned anomaly: sigmoid(relu(msg@w_ad1.T+b).w_ad2 + b)
  {
    float prod[R0];
    if (t < 128) {
      float h1[R0];
      float bb = b_ad1[t];
      #pragma unroll
      for (int r = 0; r < R0; ++r) h1[r] = bb;
      const float4* wrow = reinterpret_cast<const float4*>(w_ad1 + (size_t)t*HIDV);
      #pragma unroll 4
      for (int c4 = 0; c4 < HIDV/4; ++c4) {
        float4 w = wrow[c4];
        #pragma unroll
        for (int r = 0; r < R0; ++r)
          h1[r] += dot4(w, reinterpret_cast<const float4*>(msg_s[r])[c4]);
      }
      float wa2 = w_ad2[t];
      #pragma unroll
      for (int r = 0; r < R0; ++r) prod[r] = fmaxf(h1[r], 0.f) * wa2;
    } else {
      #pragma unroll
      for (int r = 0; r < R0; ++r) prod[r] = 0.f;
    }
    #pragma unroll
    for (int r = 0; r < R0; ++r) prod[r] = red64f(prod[r]);
    if (lane == 0) {
      #pragma unroll
      for (int r = 0; r < R0; ++r) redw[wv][r] = prod[r];
    }
    __syncthreads();
    if (t < R0) {
      int b = b0 + t;
      if (b < B) {
        float x = redw[0][t] + redw[1][t] + redw[2][t] + redw[3][t] + b_ad2[0];
        la_ws[b] = 1.f / (1.f + expf(-x));
      }
    }
  }
}

// ---------------- K1: one wave per b; zero LDS, zero syncthreads ----------------
__global__ __launch_bounds__(256) void k1_stream(
    const float* __restrict__ storage, const float* __restrict__ msg,
    const float* __restrict__ qk_ws,
    float* __restrict__ upd,
    float* __restrict__ mean_ws, float* __restrict__ pv_ws,
    float* __restrict__ se_ws, float* __restrict__ s0c_ws,
    float* __restrict__ stat_ws, int B)
{
  const int t = threadIdx.x, lane = t & 63, wv = t >> 6;
  const int b = blockIdx.x * 4 + wv;
  if (b >= B) return;
  const int c0 = lane * 4;

  const float* __restrict__ srow = storage + (size_t)b*KR*HIDV;
  float* __restrict__ urow = upd + (size_t)b*KR*HIDV;
  const float* __restrict__ qkp = qk_ws + (size_t)b*(NH*HIDV);

  const f4 qk0 = *reinterpret_cast<const f4*>(qkp + 0*HIDV + c0);
  const f4 qk1 = *reinterpret_cast<const f4*>(qkp + 1*HIDV + c0);
  const f4 qk2 = *reinterpret_cast<const f4*>(qkp + 2*HIDV + c0);
  const f4 qk3 = *reinterpret_cast<const f4*>(qkp + 3*HIDV + c0);
  const f4 msgr = *reinterpret_cast<const f4*>(msg + (size_t)b*HIDV + c0);

  // s0coef[h] = qk[h] . msg
  {
    float a0 = red64f(dotf4(qk0, msgr));
    float a1 = red64f(dotf4(qk1, msgr));
    float a2 = red64f(dotf4(qk2, msgr));
    float a3 = red64f(dotf4(qk3, msgr));
    if (lane == 0) {
      s0c_ws[(size_t)b*NH + 0] = a0;
      s0c_ws[(size_t)b*NH + 1] = a1;
      s0c_ws[(size_t)b*NH + 2] = a2;
      s0c_ws[(size_t)b*NH + 3] = a3;
    }
  }

  f4 S1 = {0.f,0.f,0.f,0.f}, S2 = {0.f,0.f,0.f,0.f};
  f4 pv0 = {0.f,0.f,0.f,0.f}, pv1 = {0.f,0.f,0.f,0.f};
  f4 pv2 = {0.f,0.f,0.f,0.f}, pv3 = {0.f,0.f,0.f,0.f};
  float se0 = 0.f, se1 = 0.f, se2 = 0.f, se3 = 0.f;
  float cntf = 0.f;
  float dw = 1.f;

  f4 x[4], xn[4];
  #pragma unroll
  for (int rr = 0; rr < 4; ++rr)
    x[rr] = ntload4(srow + (size_t)rr*HIDV + c0);

  for (int g = 0; g < 16; ++g) {
    const int j0 = g*4;
    if (g < 15) {
      #pragma unroll
      for (int rr = 0; rr < 4; ++rr)
        xn[rr] = ntload4(srow + (size_t)(j0+4+rr)*HIDV + c0);
    }
    #pragma unroll
    for (int rr = 0; rr < 4; ++rr) {
      const int j = j0 + rr;
      f4 xx = x[rr];
      unsigned long long bal = __ballot(xx.x != 0.f || xx.y != 0.f ||
                                        xx.z != 0.f || xx.w != 0.f);
      if (bal) {  // wave-uniform
        cntf += 1.f;
        S1 += xx;
        S2 += xx*xx;
      }
      float sp0 = dotf4(qk0, xx);
      float sp1 = dotf4(qk1, xx);
      float sp2 = dotf4(qk2, xx);
      float sp3 = dotf4(qk3, xx);
      sp0 = red64f(sp0); sp1 = red64f(sp1);
      sp2 = red64f(sp2); sp3 = red64f(sp3);
      if (j < KR-1) {
        f4 u = xx * dw;
        ntstore4(urow + (size_t)(j+1)*HIDV + c0, u);
        float f = dw * 0.125f;
        float e0 = __expf(sp0*f), e1 = __expf(sp1*f);
        float e2 = __expf(sp2*f), e3 = __expf(sp3*f);
        se0 += e0; se1 += e1; se2 += e2; se3 += e3;
        pv0 += xx * (e0*dw); pv1 += xx * (e1*dw);
        pv2 += xx * (e2*dw); pv3 += xx * (e3*dw);
      }
      dw *= 0.95f;
    }
    if (g < 15) {
      #pragma unroll
      for (int rr = 0; rr < 4; ++rr) x[rr] = xn[rr];
    }
  }

  // per-lane epilogue: mean/std/z for this lane's 4 columns
  const float msum = cntf + 1e-8f;
  const float inv = 1.f / msum;
  f4 mn;
  mn.x = S1.x*inv; mn.y = S1.y*inv; mn.z = S1.z*inv; mn.w = S1.w*inv;
  *reinterpret_cast<f4*>(mean_ws + (size_t)b*HIDV + c0) = mn;

  float ind = 0.f;
  {
    float vx = S2.x - 2.f*mn.x*S1.x + mn.x*mn.x*cntf;
    float vy = S2.y - 2.f*mn.y*S1.y + mn.y*mn.y*cntf;
    float vz = S2.z - 2.f*mn.z*S1.z + mn.z*mn.z*cntf;
    float vw = S2.w - 2.f*mn.w*S1.w + mn.w*mn.w*cntf;
    float sx = sqrtf(fmaxf(vx,0.f)*inv), sy = sqrtf(fmaxf(vy,0.f)*inv);
    float sz = sqrtf(fmaxf(vz,0.f)*inv), sw = sqrtf(fmaxf(vw,0.f)*inv);
    ind += (fabsf((msgr.x-mn.x)/(sx+1e-8f)) > 2.f) ? 1.f : 0.f;
    ind += (fabsf((msgr.y-mn.y)/(sy+1e-8f)) > 2.f) ? 1.f : 0.f;
    ind += (fabsf((msgr.z-mn.z)/(sz+1e-8f)) > 2.f) ? 1.f : 0.f;
    ind += (fabsf((msgr.w-mn.w)/(sw+1e-8f)) > 2.f) ? 1.f : 0.f;
  }
  ind = red64f(ind);

  float* pvp = pv_ws + (size_t)b*(NH*HIDV);
  *reinterpret_cast<f4*>(pvp + 0*HIDV + c0) = pv0;
  *reinterpret_cast<f4*>(pvp + 1*HIDV + c0) = pv1;
  *reinterpret_cast<f4*>(pvp + 2*HIDV + c0) = pv2;
  *reinterpret_cast<f4*>(pvp + 3*HIDV + c0) = pv3;

  if (lane == 0) {
    se_ws[(size_t)b*NH + 0] = se0;
    se_ws[(size_t)b*NH + 1] = se1;
    se_ws[(size_t)b*NH + 2] = se2;
    se_ws[(size_t)b*NH + 3] = se3;
    stat_ws[b] = ind * (1.f/256.f);
  }
}

// ---------------- K3: imp MLP, row0, finish softmax, pooled V + out proj ----------------
__global__ __launch_bounds__(256) void k3_out(
    const float* __restrict__ msg,
    const float* __restrict__ mean_ws, const float* __restrict__ pv_ws,
    const float* __restrict__ se_ws, const float* __restrict__ s0c_ws,
    const float* __restrict__ stat_ws, const float* __restrict__ la_ws,
    const float* __restrict__ w_im1, const float* __restrict__ b_im1,
    const float* __restrict__ w_im2, const float* __restrict__ b_im2,
    const float* __restrict__ ipw, const float* __restrict__ ipb,
    const float* __restrict__ opw, const float* __restrict__ opb,
    float* __restrict__ upd, float* __restrict__ agg, int B)
{
  __shared__ float msg_s[8][HIDV];
  __shared__ float mc_s[8][HIDV];      // mean in phase1, ctx in phase3
  __shared__ float pu_s[8][NH*HIDV];
  __shared__ float redw[4][8];
  __shared__ float imp_s[8];
  __shared__ float se_sh[8][NH];
  __shared__ float s0_sh[8][NH];

  const int t = threadIdx.x, lane = t & 63, wv = t >> 6;
  const int b0 = blockIdx.x * 8;

  // prefetch pv column t for all 8 rows x 4 heads (hides latency under MLP)
  float pvr[8][NH];
  #pragma unroll
  for (int r = 0; r < 8; ++r) {
    int b = b0 + r; if (b >= B) b = B - 1;
    #pragma unroll
    for (int h = 0; h < NH; ++h)
      pvr[r][h] = pv_ws[(size_t)b*(NH*HIDV) + h*HIDV + t];
  }

  #pragma unroll
  for (int r = 0; r < 8; ++r) {
    int b = b0 + r;
    msg_s[r][t] = (b < B) ? msg[(size_t)b*HIDV + t] : 0.f;
    mc_s[r][t]  = (b < B) ? mean_ws[(size_t)b*HIDV + t] : 0.f;
  }
  if (t < 8*NH) {
    int r = t >> 2, h = t & 3;
    int b = b0 + r;
    se_sh[r][h] = (b < B) ? se_ws[(size_t)b*NH + h] : 0.f;
    s0_sh[r][h] = (b < B) ? s0c_ws[(size_t)b*NH + h] : 0.f;
  }
  __syncthreads();

  // g = relu([msg,mean] @ w_im1.T + b), imp = softplus(g.w_im2+b)*(1+anom)
  {
    float g[8];
    float bi = b_im1[t];
    #pragma unroll
    for (int r = 0; r < 8; ++r) g[r] = bi;
    const float4* w1 = reinterpret_cast<const float4*>(w_im1 + (size_t)t*(2*HIDV));
    #pragma unroll 4
    for (int c4 = 0; c4 < HIDV/4; ++c4) {
      float4 w = w1[c4];
      #pragma unroll
      for (int r = 0; r < 8; ++r)
        g[r] += dot4(w, reinterpret_cast<const float4*>(msg_s[r])[c4]);
    }
    #pragma unroll 4
    for (int c4 = 0; c4 < HIDV/4; ++c4) {
      float4 w = w1[HIDV/4 + c4];
      #pragma unroll
      for (int r = 0; r < 8; ++r)
        g[r] += dot4(w, reinterpret_cast<const float4*>(mc_s[r])[c4]);
    }
    float w2 = w_im2[t];
    float prod[8];
    #pragma unroll
    for (int r = 0; r < 8; ++r) prod[r] = red64f(fmaxf(g[r], 0.f) * w2);
    if (lane == 0) {
      #pragma unroll
      for (int r = 0; r < 8; ++r) redw[wv][r] = prod[r];
    }
    __syncthreads();
    if (t < 8) {
      int b = b0 + t;
      float x = redw[0][t]+redw[1][t]+redw[2][t]+redw[3][t] + b_im2[0];
      float sp = fmaxf(x, 0.f) + log1pf(expf(-fabsf(x)));
      float an = (b < B) ? (0.5f*stat_ws[b] + 0.5f*la_ws[b]) : 0.f;
      imp_s[t] = sp * (1.f + an);
    }
    __syncthreads();
  }

  // row0 of updated + pu = attn0*u0 + pv1/denom
  #pragma unroll
  for (int r = 0; r < 8; ++r) {
    int b = b0 + r;
    if (b < B) upd[(size_t)b*KR*HIDV + t] = msg_s[r][t] * imp_s[r];
  }
  #pragma unroll
  for (int r = 0; r < 8; ++r) {
    float impr = imp_s[r];
    #pragma unroll
    for (int h = 0; h < NH; ++h) {
      float s0 = impr * s0_sh[r][h] * 0.125f;
      float e0 = __expf(s0);
      float den = e0 + se_sh[r][h];
      float inv = 1.f / den;
      float a0 = e0 * inv;
      pu_s[r][h*HIDV + t] = a0*impr*msg_s[r][t] + pvr[r][h]*inv;
    }
  }
  __syncthreads();

  // ctx_out[t] = bv[t] + wv_row[t] . pu[head(t)]   (into mc_s)
  {
    float co[8];
    float bv = ipb[2*HIDV + t];
    #pragma unroll
    for (int r = 0; r < 8; ++r) co[r] = bv;
    const int hh = t >> 6;
    const float4* wrow = reinterpret_cast<const float4*>(ipw + (size_t)(2*HIDV + t)*HIDV);
    #pragma unroll 4
    for (int c4 = 0; c4 < HIDV/4; ++c4) {
      float4 w = wrow[c4];
      #pragma unroll
      for (int r = 0; r < 8; ++r)
        co[r] += dot4(w, reinterpret_cast<const float4*>(&pu_s[r][hh*HIDV])[c4]);
    }
    __syncthreads();
    #pragma unroll
    for (int r = 0; r < 8; ++r) mc_s[r][t] = co[r];
  }
  __syncthreads();

  // aggregated = ctx_out @ out_w.T + out_b
  {
    float ag[8];
    float bo = opb[t];
    #pragma unroll
    for (int r = 0; r < 8; ++r) ag[r] = bo;
    const float4* wrow = reinterpret_cast<const float4*>(opw + (size_t)t*HIDV);
    #pragma unroll 4
    for (int c4 = 0; c4 < HIDV/4; ++c4) {
      float4 w = wrow[c4];
      #pragma unroll
      for (int r = 0; r < 8; ++r)
        ag[r] += dot4(w, reinterpret_cast<const float4*>(mc_s[r])[c4]);
    }
    #pragma unroll
    for (int r = 0; r < 8; ++r) {
      int b = b0 + r;
      if (b < B) agg[(size_t)b*HIDV + t] = ag[r];
    }
  }
}

extern "C" void kernel_launch(void* const* d_in, const int* in_sizes, int n_in,
                              void* d_out, int out_size, void* d_ws, size_t ws_size,
                              hipStream_t stream) {
  const float* storage = (const float*)d_in[0];
  const float* msg     = (const float*)d_in[1];
  const float* w_ad1   = (const float*)d_in[2];
  const float* b_ad1   = (const float*)d_in[3];
  const float* w_ad2   = (const float*)d_in[4];
  const float* b_ad2   = (const float*)d_in[5];
  const float* w_im1   = (const float*)d_in[6];
  const float* b_im1   = (const float*)d_in[7];
  const float* w_im2   = (const float*)d_in[8];
  const float* b_im2   = (const float*)d_in[9];
  const float* ipw     = (const float*)d_in[10];
  const float* ipb     = (const float*)d_in[11];
  const float* opw     = (const float*)d_in[12];
  const float* opb     = (const float*)d_in[13];

  const int B = in_sizes[1] / HIDV;
  float* upd = (float*)d_out;
  float* agg = upd + (size_t)B*KR*HIDV;

  float* wsf = (float*)d_ws;
  size_t off = 0;
  float* qk   = wsf + off; off += (size_t)B*NH*HIDV;
  float* pv1  = wsf + off; off += (size_t)B*NH*HIDV;
  float* mean = wsf + off; off += (size_t)B*HIDV;
  float* se1  = wsf + off; off += (size_t)B*NH;
  float* s0c  = wsf + off; off += (size_t)B*NH;
  float* stat = wsf + off; off += (size_t)B;
  float* la   = wsf + off; off += (size_t)B;

  hipLaunchKernelGGL(k0_mlp_qk, dim3((B+R0-1)/R0), dim3(256), 0, stream,
                     msg, w_ad1, b_ad1, w_ad2, b_ad2, ipw, ipb, qk, la, B);
  hipLaunchKernelGGL(k1_stream, dim3((B+3)/4), dim3(256), 0, stream,
                     storage, msg, qk, upd, mean, pv1, se1, s0c, stat, B);
  hipLaunchKernelGGL(k3_out, dim3((B+7)/8), dim3(256), 0, stream,
                     msg, mean, pv1, se1, s0c, stat, la,
                     w_im1, b_im1, w_im2, b_im2, ipw, ipb, opw, opb,
                     upd, agg, B);
}